// Round 8
// baseline (699.391 us; speedup 1.0000x reference)
//
#include <hip/hip_runtime.h>
#include <hip/hip_bf16.h>
#include <cstdint>
#include <cstddef>

typedef __bf16 bf16_t;
typedef __bf16 bf16x8 __attribute__((ext_vector_type(8)));
typedef float f32x4 __attribute__((ext_vector_type(4)));

#define GLP(p)  (const __attribute__((address_space(1))) void*)(p)
#define LDSP(p) (__attribute__((address_space(3))) void*)(p)

static constexpr int BS   = 8;
static constexpr int SEQ  = 2048;
static constexpr int DIN  = 4096;
static constexpr int DOUT = 4096;
static constexpr int NSK  = 8;
static constexpr int RANK = 16;
static constexpr int MTOT = BS * SEQ;           // 16384

static __device__ __forceinline__ bf16x8 cvt8(float4 v0, float4 v1) {
    bf16x8 o;
    o[0] = (bf16_t)v0.x; o[1] = (bf16_t)v0.y; o[2] = (bf16_t)v0.z; o[3] = (bf16_t)v0.w;
    o[4] = (bf16_t)v1.x; o[5] = (bf16_t)v1.y; o[6] = (bf16_t)v1.z; o[7] = (bf16_t)v1.w;
    return o;
}

// ------------------------------------------------------------------
// Kernel 1: mixing weights -> Abt (A^T mixed, bf16 [b][16][4096]) and
//           Btp (B mixed transposed+padded, bf16 [b][4096][32], r>=16 zero)
// ------------------------------------------------------------------
__global__ __launch_bounds__(256) void mix_kernel(
    const float* __restrict__ logits, const int* __restrict__ task_ids,
    const float* __restrict__ lora_a, const float* __restrict__ lora_b,
    bf16_t* __restrict__ Abt, bf16_t* __restrict__ Btp) {
    int b = blockIdx.y;
    int c = blockIdx.x;
    int tid = threadIdx.x;

    int t = task_ids[b];
    float w[NSK]; float sum = 0.f;
#pragma unroll
    for (int s = 0; s < NSK; ++s) {
        float lg = logits[t * NSK + s];
        float sg = 1.f / (1.f + __expf(-lg));
        w[s] = sg; sum += sg;
    }
    float inv = 1.f / (sum + 1e-12f);
#pragma unroll
    for (int s = 0; s < NSK; ++s) w[s] *= inv;

    {
        int r = tid & 15, kk = tid >> 4;
#pragma unroll
        for (int i = 0; i < 4; ++i) {
            int k = c * 64 + i * 16 + kk;
            float acc = 0.f;
#pragma unroll
            for (int s = 0; s < NSK; ++s)
                acc += w[s] * lora_a[((size_t)s * DIN + k) * RANK + r];
            Abt[((size_t)b * RANK + r) * DIN + k] = (bf16_t)acc;
        }
    }
    {
        int n = c * 64 + (tid & 63);
        int r0 = tid >> 6;
#pragma unroll
        for (int i = 0; i < 4; ++i) {
            int rr = r0 + i * 4;
            float acc = 0.f;
#pragma unroll
            for (int s = 0; s < NSK; ++s)
                acc += w[s] * lora_b[((size_t)s * RANK + rr) * DOUT + n];
            Btp[((size_t)b * DOUT + n) * 32 + rr] = (bf16_t)acc;
            Btp[((size_t)b * DOUT + n) * 32 + 16 + rr] = (bf16_t)0.f;
        }
    }
}

// ------------------------------------------------------------------
// Kernel 2: W f32 -> bf16
// ------------------------------------------------------------------
__global__ __launch_bounds__(256) void convw_kernel(const float* __restrict__ W,
                                                    bf16_t* __restrict__ Wb) {
    size_t g = (size_t)blockIdx.x * 256 + threadIdx.x;
    const float4* src = (const float4*)W;
    float4 v0 = src[g * 2], v1 = src[g * 2 + 1];
    *(bf16x8*)(Wb + g * 8) = cvt8(v0, v1);
}

// ------------------------------------------------------------------
// Kernel 3: fused x->bf16 conversion + t = (x @ A_mix)/16, padded to K=32
// ------------------------------------------------------------------
template<bool XPRE>
__global__ __launch_bounds__(256) void tconv_kernel(
    const float* __restrict__ x, const bf16_t* __restrict__ Abt,
    bf16_t* __restrict__ xb, bf16_t* __restrict__ tpad) {
    __shared__ __align__(16) bf16_t As[64 * 64];
    __shared__ __align__(16) bf16_t Aa[16 * 64];

    int row0 = blockIdx.x * 64;
    int b = row0 >> 11;
    int tid = threadIdx.x;
    int w = tid >> 6, l = tid & 63;
    const bf16_t* Ab = Abt + (size_t)b * RANK * DIN;

    f32x4 acc = {0.f, 0.f, 0.f, 0.f};

    for (int k0 = 0; k0 < DIN; k0 += 64) {
#pragma unroll
        for (int i = 0; i < 2; ++i) {
            int flat = i * 256 + tid;
            int row = flat >> 3, c8 = flat & 7;
            const float* src = x + (size_t)(row0 + row) * DIN + k0 + c8 * 8;
            float4 v0 = *(const float4*)src;
            float4 v1 = *(const float4*)(src + 4);
            bf16x8 o = cvt8(v0, v1);
            *(bf16x8*)(&As[flat * 8]) = o;
            if (XPRE)
                *(bf16x8*)(xb + (size_t)(row0 + row) * DIN + k0 + c8 * 8) = o;
        }
        if (tid < 128) {
            int r = tid >> 3, c8 = tid & 7;
            __builtin_amdgcn_global_load_lds(GLP(Ab + (size_t)r * DIN + k0 + c8 * 8),
                                             LDSP(&Aa[tid * 8]), 16, 0, 0);
        }
        __syncthreads();
#pragma unroll
        for (int s = 0; s < 2; ++s) {
            int kr = s * 32 + (l >> 4) * 8;
            bf16x8 a = *(const bf16x8*)(&As[(w * 16 + (l & 15)) * 64 + kr]);
            bf16x8 bb = *(const bf16x8*)(&Aa[(l & 15) * 64 + kr]);
            acc = __builtin_amdgcn_mfma_f32_16x16x32_bf16(a, bb, acc, 0, 0, 0);
        }
        __syncthreads();
    }
    int r = l & 15;
    int rowb = w * 16 + (l >> 4) * 4;
#pragma unroll
    for (int j = 0; j < 4; ++j) {
        int gm = row0 + rowb + j;
        tpad[(size_t)gm * 32 + r] = (bf16_t)(acc[j] * 0.0625f);
        tpad[(size_t)gm * 32 + 16 + r] = (bf16_t)0.f;
    }
}

// ------------------------------------------------------------------
// Kernel 4: 256x256 8-phase GEMM (m201-style), global-quadrant phases.
//   out = xb @ Wb^T + bias + tpad @ Btp^T
//   Phase (QM,QN): ds_reads for that quadrant ; stage 1 half-chunk of
//   tile j+1 ; vmcnt(4) ; barrier ; lgkm(0) ; setprio(1) 16 MFMA ; barrier.
//   vmcnt(4) keeps exactly 2 chunks (4 loads) in flight — never drains.
// ------------------------------------------------------------------
#define VMCNT4 asm volatile("s_waitcnt vmcnt(4)" ::: "memory")
#define VMCNT0 asm volatile("s_waitcnt vmcnt(0)" ::: "memory")
#define LGKM0  asm volatile("s_waitcnt lgkmcnt(0)" ::: "memory")
#define SBAR   __builtin_amdgcn_s_barrier()
#define SCHEDB __builtin_amdgcn_sched_barrier(0)

#define MFMA_Q(AREG, BREG, QM, QN)                                             \
    _Pragma("unroll") for (int s_ = 0; s_ < 2; ++s_)                           \
    _Pragma("unroll") for (int i_ = 0; i_ < 4; ++i_)                           \
    _Pragma("unroll") for (int jj_ = 0; jj_ < 2; ++jj_)                        \
        acc[(QM)*4 + i_][(QN)*2 + jj_] =                                       \
            __builtin_amdgcn_mfma_f32_16x16x32_bf16(                           \
                AREG[i_][s_], BREG[jj_][s_], acc[(QM)*4 + i_][(QN)*2 + jj_],   \
                0, 0, 0);

__global__ __launch_bounds__(512, 2) void gemm8_kernel(
    const bf16_t* __restrict__ xb, const bf16_t* __restrict__ Wb,
    const float* __restrict__ bias,
    const bf16_t* __restrict__ tpad, const bf16_t* __restrict__ Btp,
    float* __restrict__ out) {
    __shared__ __align__(16) bf16_t ldsA[2][256 * 64];   // 64 KiB
    __shared__ __align__(16) bf16_t ldsB[2][256 * 64];   // 64 KiB

    int tid = threadIdx.x;
    int w = tid >> 6, l = tid & 63;
    int wm = w >> 2, wn = w & 3;        // 2M x 4N waves
    int l4 = l >> 4, l15 = l & 15;

    // XCD-bijective swizzle: nwg = 1024, 8 XCDs, 128 per XCD
    int orig = blockIdx.x;
    int id = (orig & 7) * 128 + (orig >> 3);
    int mb = id >> 4, nb = id & 15;
    int row0 = mb * 256, col0 = nb * 256;
    int b = row0 >> 11;

    f32x4 acc[8][4] = {};

    // stage half h (128 rows x 64 k) of A/B for K-tile kt into buffer c.
    // 2 loads/thread. Dest linear, source pre-swizzled (rule 21).
    auto stageHalfA = [&](int kt, int c, int h) {
        int k0 = kt * 64;
#pragma unroll
        for (int ld = 0; ld < 2; ++ld) {
            int flat = ld * 512 + tid;       // 0..1023
            int r = flat >> 3;               // 0..127
            int sc = (flat & 7) ^ (r & 7);
            __builtin_amdgcn_global_load_lds(
                GLP(xb + (size_t)(row0 + h * 128 + r) * DIN + k0 + sc * 8),
                LDSP(&ldsA[c][h * 8192 + flat * 8]), 16, 0, 0);
        }
    };
    auto stageHalfB = [&](int kt, int c, int h) {
        int k0 = kt * 64;
#pragma unroll
        for (int ld = 0; ld < 2; ++ld) {
            int flat = ld * 512 + tid;
            int r = flat >> 3;
            int sc = (flat & 7) ^ (r & 7);
            __builtin_amdgcn_global_load_lds(
                GLP(Wb + (size_t)(col0 + h * 128 + r) * DIN + k0 + sc * 8),
                LDSP(&ldsB[c][h * 8192 + flat * 8]), 16, 0, 0);
        }
    };
    // adapter tiles (256 x 32, linear layout), 2 loads/thread each
    auto stageAdpA = [&](int c) {
#pragma unroll
        for (int ld = 0; ld < 2; ++ld) {
            int flat = ld * 512 + tid;
            int r = flat >> 2, c4 = flat & 3;
            __builtin_amdgcn_global_load_lds(
                GLP(tpad + (size_t)(row0 + r) * 32 + c4 * 8),
                LDSP(&ldsA[c][flat * 8]), 16, 0, 0);
        }
    };
    auto stageAdpB = [&](int c) {
#pragma unroll
        for (int ld = 0; ld < 2; ++ld) {
            int flat = ld * 512 + tid;
            int r = flat >> 2, c4 = flat & 3;
            __builtin_amdgcn_global_load_lds(
                GLP(Btp + ((size_t)b * DOUT + col0 + r) * 32 + c4 * 8),
                LDSP(&ldsB[c][flat * 8]), 16, 0, 0);
        }
    };

    auto loadA = [&](const bf16_t* base, int QM, bf16x8 (&ar)[4][2]) {
#pragma unroll
        for (int i = 0; i < 4; ++i) {
            int row = QM * 128 + wm * 64 + i * 16 + l15;
#pragma unroll
            for (int s = 0; s < 2; ++s)
                ar[i][s] = *(const bf16x8*)(base + row * 64 +
                                            (((s * 4 + l4) ^ (l15 & 7)) << 3));
        }
    };
    auto loadB = [&](const bf16_t* base, int QN, bf16x8 (&br)[2][2]) {
#pragma unroll
        for (int jj = 0; jj < 2; ++jj) {
            int row = QN * 128 + wn * 32 + jj * 16 + l15;
#pragma unroll
            for (int s = 0; s < 2; ++s)
                br[jj][s] = *(const bf16x8*)(base + row * 64 +
                                             (((s * 4 + l4) ^ (l15 & 7)) << 3));
        }
    };

    // prologue: tile 0 chunks, oldest-first matching consumption order
    stageHalfA(0, 0, 0);
    stageHalfB(0, 0, 0);
    stageHalfB(0, 0, 1);
    stageHalfA(0, 0, 1);
    VMCNT4;       // Ah0[0], Bh0[0] landed; Bh1[0], Ah1[0] in flight
    SCHEDB; SBAR; SCHEDB;

#pragma unroll 1
    for (int j = 0; j < 64; ++j) {
        int c = j & 1, nc = c ^ 1;
        const bf16_t* A_c = &ldsA[c][0];
        const bf16_t* B_c = &ldsB[c][0];
        bf16x8 aA[4][2], aB[4][2], bA[2][2], bB[2][2];

        // ---- phase 0: quadrant (0,0) ----
        loadA(A_c, 0, aA);
        loadB(B_c, 0, bA);
        if (j < 63) stageHalfA(j + 1, nc, 0); else stageAdpA(nc);
        VMCNT4; SCHEDB; SBAR;
        LGKM0; SCHEDB;
        __builtin_amdgcn_s_setprio(1);
        MFMA_Q(aA, bA, 0, 0);
        __builtin_amdgcn_s_setprio(0);
        SCHEDB; SBAR;

        // ---- phase 1: quadrant (0,1) ----
        loadB(B_c, 1, bB);
        if (j < 63) stageHalfB(j + 1, nc, 0); else stageAdpB(nc);
        VMCNT4; SCHEDB; SBAR;
        LGKM0; SCHEDB;
        __builtin_amdgcn_s_setprio(1);
        MFMA_Q(aA, bB, 0, 1);
        __builtin_amdgcn_s_setprio(0);
        SCHEDB; SBAR;

        // ---- phase 2: quadrant (1,1) ----
        loadA(A_c, 1, aB);
        if (j < 63) stageHalfB(j + 1, nc, 1);
        VMCNT4; SCHEDB; SBAR;
        LGKM0; SCHEDB;
        __builtin_amdgcn_s_setprio(1);
        MFMA_Q(aB, bB, 1, 1);
        __builtin_amdgcn_s_setprio(0);
        SCHEDB; SBAR;

        // ---- phase 3: quadrant (1,0) — all operands already in regs ----
        if (j < 63) stageHalfA(j + 1, nc, 1);
        VMCNT4; SCHEDB; SBAR; SCHEDB;
        __builtin_amdgcn_s_setprio(1);
        MFMA_Q(aB, bA, 1, 0);
        __builtin_amdgcn_s_setprio(0);
        SCHEDB; SBAR;
    }

    // drain adapter loads (in buf 0), then the K=32 adapter MFMA step
    VMCNT0; SCHEDB; SBAR; SCHEDB;
    {
        const bf16_t* A0 = &ldsA[0][0];
        const bf16_t* B0 = &ldsB[0][0];
        bf16x8 aa[8]; bf16x8 bb[4];
#pragma unroll
        for (int ai = 0; ai < 8; ++ai) {
            int row = (ai >> 2) * 128 + wm * 64 + (ai & 3) * 16 + l15;
            aa[ai] = *(const bf16x8*)(A0 + row * 32 + l4 * 8);
        }
#pragma unroll
        for (int bj = 0; bj < 4; ++bj) {
            int row = (bj >> 1) * 128 + wn * 32 + (bj & 1) * 16 + l15;
            bb[bj] = *(const bf16x8*)(B0 + row * 32 + l4 * 8);
        }
#pragma unroll
        for (int ai = 0; ai < 8; ++ai)
#pragma unroll
            for (int bj = 0; bj < 4; ++bj)
                acc[ai][bj] = __builtin_amdgcn_mfma_f32_16x16x32_bf16(
                    aa[ai], bb[bj], acc[ai][bj], 0, 0, 0);
    }

    // ---- epilogue: + bias, store f32 ----
#pragma unroll
    for (int ai = 0; ai < 8; ++ai) {
        int gm = row0 + (ai >> 2) * 128 + wm * 64 + (ai & 3) * 16 + l4 * 4;
#pragma unroll
        for (int bj = 0; bj < 4; ++bj) {
            int gn = col0 + (bj >> 1) * 128 + wn * 32 + (bj & 1) * 16 + l15;
            float bsv = bias[gn];
#pragma unroll
            for (int q = 0; q < 4; ++q)
                out[(size_t)(gm + q) * DOUT + gn] = acc[ai][bj][q] + bsv;
        }
    }
}

// ------------------------------------------------------------------
// Fallback GEMM (m97 structure) for small-workspace paths
// ------------------------------------------------------------------
template<bool WPRE>
__global__ __launch_bounds__(256) void gemm_kernel(
    const float* __restrict__ xf,
    const float* __restrict__ Wf, const bf16_t* __restrict__ Wb,
    const float* __restrict__ bias,
    const bf16_t* __restrict__ tpad, const bf16_t* __restrict__ Btp,
    float* __restrict__ out) {
    __shared__ __align__(16) bf16_t As[128 * 64];
    __shared__ __align__(16) bf16_t Bs[128 * 64];

    int orig = blockIdx.x;
    int id = (orig & 7) * 512 + (orig >> 3);
    int mb = id >> 5, nb = id & 31;
    int row0 = mb * 128, col0 = nb * 128;
    int b = row0 >> 11;

    int tid = threadIdx.x;
    int w = tid >> 6, l = tid & 63;
    int wm = w >> 1, wn = w & 1;

    f32x4 acc[4][4] = {};

    for (int k0 = 0; k0 < DIN; k0 += 64) {
#pragma unroll
        for (int i = 0; i < 4; ++i) {
            int flat = i * 256 + tid;
            int row = flat >> 3, c8 = flat & 7;
            const float* src = xf + (size_t)(row0 + row) * DIN + k0 + c8 * 8;
            float4 v0 = *(const float4*)src;
            float4 v1 = *(const float4*)(src + 4);
            *(bf16x8*)(&As[flat * 8]) = cvt8(v0, v1);
        }
        if constexpr (WPRE) {
#pragma unroll
            for (int i = 0; i < 4; ++i) {
                int flat = i * 256 + tid;
                int row = flat >> 3, c8 = flat & 7;
                __builtin_amdgcn_global_load_lds(
                    GLP(Wb + (size_t)(col0 + row) * DIN + k0 + c8 * 8),
                    LDSP(&Bs[flat * 8]), 16, 0, 0);
            }
        } else {
#pragma unroll
            for (int i = 0; i < 4; ++i) {
                int flat = i * 256 + tid;
                int row = flat >> 3, c8 = flat & 7;
                const float* src = Wf + (size_t)(col0 + row) * DIN + k0 + c8 * 8;
                float4 v0 = *(const float4*)src;
                float4 v1 = *(const float4*)(src + 4);
                *(bf16x8*)(&Bs[flat * 8]) = cvt8(v0, v1);
            }
        }
        __syncthreads();
#pragma unroll
        for (int s = 0; s < 2; ++s) {
            int kr = s * 32 + (l >> 4) * 8;
            bf16x8 a[4], bf[4];
#pragma unroll
            for (int i = 0; i < 4; ++i)
                a[i] = *(const bf16x8*)(&As[(wm * 64 + i * 16 + (l & 15)) * 64 + kr]);
#pragma unroll
            for (int j = 0; j < 4; ++j)
                bf[j] = *(const bf16x8*)(&Bs[(wn * 64 + j * 16 + (l & 15)) * 64 + kr]);
#pragma unroll
            for (int i = 0; i < 4; ++i)
#pragma unroll
                for (int j = 0; j < 4; ++j)
                    acc[i][j] = __builtin_amdgcn_mfma_f32_16x16x32_bf16(a[i], bf[j], acc[i][j], 0, 0, 0);
        }
        __syncthreads();
    }

    {
#pragma unroll
        for (int i = 0; i < 2; ++i) {
            int flat = i * 256 + tid;
            int row = flat >> 2, c8 = flat & 3;
            __builtin_amdgcn_global_load_lds(
                GLP(tpad + (size_t)(row0 + row) * 32 + c8 * 8),
                LDSP(&As[flat * 8]), 16, 0, 0);
            __builtin_amdgcn_global_load_lds(
                GLP(Btp + ((size_t)b * DOUT + col0 + row) * 32 + c8 * 8),
                LDSP(&Bs[flat * 8]), 16, 0, 0);
        }
        __syncthreads();
        int kr = (l >> 4) * 8;
        bf16x8 a[4], bf[4];
#pragma unroll
        for (int i = 0; i < 4; ++i)
            a[i] = *(const bf16x8*)(&As[(wm * 64 + i * 16 + (l & 15)) * 32 + kr]);
#pragma unroll
        for (int j = 0; j < 4; ++j)
            bf[j] = *(const bf16x8*)(&Bs[(wn * 64 + j * 16 + (l & 15)) * 32 + kr]);
#pragma unroll
        for (int i = 0; i < 4; ++i)
#pragma unroll
            for (int j = 0; j < 4; ++j)
                acc[i][j] = __builtin_amdgcn_mfma_f32_16x16x32_bf16(a[i], bf[j], acc[i][j], 0, 0, 0);
    }

#pragma unroll
    for (int i = 0; i < 4; ++i) {
        int gm = row0 + wm * 64 + i * 16 + (l >> 4) * 4;
#pragma unroll
        for (int j = 0; j < 4; ++j) {
            int gn = col0 + wn * 64 + j * 16 + (l & 15);
            float bs = bias[gn];
#pragma unroll
            for (int q = 0; q < 4; ++q)
                out[(size_t)(gm + q) * DOUT + gn] = acc[i][j][q] + bs;
        }
    }
}

// ------------------------------------------------------------------
extern "C" void kernel_launch(void* const* d_in, const int* in_sizes, int n_in,
                              void* d_out, int out_size, void* d_ws, size_t ws_size,
                              hipStream_t stream) {
    const float* x        = (const float*)d_in[0];
    const int*   task_ids = (const int*)d_in[1];
    const float* W        = (const float*)d_in[2];
    const float* bias     = (const float*)d_in[3];
    const float* logits   = (const float*)d_in[4];
    const float* lora_a   = (const float*)d_in[5];
    const float* lora_b   = (const float*)d_in[6];
    float* out = (float*)d_out;

    char* ws = (char*)d_ws;
    size_t off = 0;
    auto alloc = [&](size_t bytes) {
        char* p = ws + off;
        off += (bytes + 255) & ~(size_t)255;
        return p;
    };
    bf16_t* Abt  = (bf16_t*)alloc((size_t)BS * RANK * DIN * 2);
    bf16_t* Btp  = (bf16_t*)alloc((size_t)BS * DOUT * 32 * 2);
    bf16_t* tpad = (bf16_t*)alloc((size_t)MTOT * 32 * 2);
    bf16_t* Wb   = (bf16_t*)alloc((size_t)DOUT * DIN * 2);
    size_t w_end = off;
    bf16_t* xb   = (bf16_t*)alloc((size_t)MTOT * DIN * 2);
    size_t full_end = off;

    bool wpre = ws_size >= w_end;
    bool xpre = ws_size >= full_end;

    mix_kernel<<<dim3(64, 8), 256, 0, stream>>>(logits, task_ids, lora_a, lora_b, Abt, Btp);
    if (wpre)
        convw_kernel<<<(DOUT * DIN / 8) / 256, 256, 0, stream>>>(W, Wb);
    if (xpre)
        tconv_kernel<true><<<MTOT / 64, 256, 0, stream>>>(x, Abt, xb, tpad);
    else
        tconv_kernel<false><<<MTOT / 64, 256, 0, stream>>>(x, Abt, nullptr, tpad);

    if (xpre) {
        int nblk = (MTOT / 256) * (DOUT / 256);   // 1024
        gemm8_kernel<<<nblk, 512, 0, stream>>>(xb, Wb, bias, tpad, Btp, out);
    } else {
        int nblk = (MTOT / 128) * (DOUT / 128);   // 4096
        if (wpre)
            gemm_kernel<true><<<nblk, 256, 0, stream>>>(x, W, Wb, bias, tpad, Btp, out);
        else
            gemm_kernel<false><<<nblk, 256, 0, stream>>>(x, W, Wb, bias, tpad, Btp, out);
    }
}

// Round 9
// 611.826 us; speedup vs baseline: 1.1431x; 1.1431x over previous
//
#include <hip/hip_runtime.h>
#include <hip/hip_bf16.h>
#include <cstdint>
#include <cstddef>

typedef __bf16 bf16_t;
typedef __bf16 bf16x8 __attribute__((ext_vector_type(8)));
typedef float f32x4 __attribute__((ext_vector_type(4)));

#define GLP(p)  (const __attribute__((address_space(1))) void*)(p)
#define LDSP(p) (__attribute__((address_space(3))) void*)(p)

static constexpr int BS   = 8;
static constexpr int SEQ  = 2048;
static constexpr int DIN  = 4096;
static constexpr int DOUT = 4096;
static constexpr int NSK  = 8;
static constexpr int RANK = 16;
static constexpr int MTOT = BS * SEQ;           // 16384

static __device__ __forceinline__ bf16x8 cvt8(float4 v0, float4 v1) {
    bf16x8 o;
    o[0] = (bf16_t)v0.x; o[1] = (bf16_t)v0.y; o[2] = (bf16_t)v0.z; o[3] = (bf16_t)v0.w;
    o[4] = (bf16_t)v1.x; o[5] = (bf16_t)v1.y; o[6] = (bf16_t)v1.z; o[7] = (bf16_t)v1.w;
    return o;
}

// ------------------------------------------------------------------
// Kernel 1: mixing weights
// ------------------------------------------------------------------
__global__ __launch_bounds__(256) void mix_kernel(
    const float* __restrict__ logits, const int* __restrict__ task_ids,
    const float* __restrict__ lora_a, const float* __restrict__ lora_b,
    bf16_t* __restrict__ Abt, bf16_t* __restrict__ Btp) {
    int b = blockIdx.y;
    int c = blockIdx.x;
    int tid = threadIdx.x;

    int t = task_ids[b];
    float w[NSK]; float sum = 0.f;
#pragma unroll
    for (int s = 0; s < NSK; ++s) {
        float lg = logits[t * NSK + s];
        float sg = 1.f / (1.f + __expf(-lg));
        w[s] = sg; sum += sg;
    }
    float inv = 1.f / (sum + 1e-12f);
#pragma unroll
    for (int s = 0; s < NSK; ++s) w[s] *= inv;

    {
        int r = tid & 15, kk = tid >> 4;
#pragma unroll
        for (int i = 0; i < 4; ++i) {
            int k = c * 64 + i * 16 + kk;
            float acc = 0.f;
#pragma unroll
            for (int s = 0; s < NSK; ++s)
                acc += w[s] * lora_a[((size_t)s * DIN + k) * RANK + r];
            Abt[((size_t)b * RANK + r) * DIN + k] = (bf16_t)acc;
        }
    }
    {
        int n = c * 64 + (tid & 63);
        int r0 = tid >> 6;
#pragma unroll
        for (int i = 0; i < 4; ++i) {
            int rr = r0 + i * 4;
            float acc = 0.f;
#pragma unroll
            for (int s = 0; s < NSK; ++s)
                acc += w[s] * lora_b[((size_t)s * RANK + rr) * DOUT + n];
            Btp[((size_t)b * DOUT + n) * 32 + rr] = (bf16_t)acc;
            Btp[((size_t)b * DOUT + n) * 32 + 16 + rr] = (bf16_t)0.f;
        }
    }
}

// ------------------------------------------------------------------
// Kernel 2: W f32 -> bf16
// ------------------------------------------------------------------
__global__ __launch_bounds__(256) void convw_kernel(const float* __restrict__ W,
                                                    bf16_t* __restrict__ Wb) {
    size_t g = (size_t)blockIdx.x * 256 + threadIdx.x;
    const float4* src = (const float4*)W;
    float4 v0 = src[g * 2], v1 = src[g * 2 + 1];
    *(bf16x8*)(Wb + g * 8) = cvt8(v0, v1);
}

// ------------------------------------------------------------------
// Kernel 3: fused x->bf16 conversion + t = (x @ A_mix)/16, padded to K=32
// ------------------------------------------------------------------
template<bool XPRE>
__global__ __launch_bounds__(256) void tconv_kernel(
    const float* __restrict__ x, const bf16_t* __restrict__ Abt,
    bf16_t* __restrict__ xb, bf16_t* __restrict__ tpad) {
    __shared__ __align__(16) bf16_t As[64 * 64];
    __shared__ __align__(16) bf16_t Aa[16 * 64];

    int row0 = blockIdx.x * 64;
    int b = row0 >> 11;
    int tid = threadIdx.x;
    int w = tid >> 6, l = tid & 63;
    const bf16_t* Ab = Abt + (size_t)b * RANK * DIN;

    f32x4 acc = {0.f, 0.f, 0.f, 0.f};

    for (int k0 = 0; k0 < DIN; k0 += 64) {
#pragma unroll
        for (int i = 0; i < 2; ++i) {
            int flat = i * 256 + tid;
            int row = flat >> 3, c8 = flat & 7;
            const float* src = x + (size_t)(row0 + row) * DIN + k0 + c8 * 8;
            float4 v0 = *(const float4*)src;
            float4 v1 = *(const float4*)(src + 4);
            bf16x8 o = cvt8(v0, v1);
            *(bf16x8*)(&As[flat * 8]) = o;
            if (XPRE)
                *(bf16x8*)(xb + (size_t)(row0 + row) * DIN + k0 + c8 * 8) = o;
        }
        if (tid < 128) {
            int r = tid >> 3, c8 = tid & 7;
            __builtin_amdgcn_global_load_lds(GLP(Ab + (size_t)r * DIN + k0 + c8 * 8),
                                             LDSP(&Aa[tid * 8]), 16, 0, 0);
        }
        __syncthreads();
#pragma unroll
        for (int s = 0; s < 2; ++s) {
            int kr = s * 32 + (l >> 4) * 8;
            bf16x8 a = *(const bf16x8*)(&As[(w * 16 + (l & 15)) * 64 + kr]);
            bf16x8 bb = *(const bf16x8*)(&Aa[(l & 15) * 64 + kr]);
            acc = __builtin_amdgcn_mfma_f32_16x16x32_bf16(a, bb, acc, 0, 0, 0);
        }
        __syncthreads();
    }
    int r = l & 15;
    int rowb = w * 16 + (l >> 4) * 4;
#pragma unroll
    for (int j = 0; j < 4; ++j) {
        int gm = row0 + rowb + j;
        tpad[(size_t)gm * 32 + r] = (bf16_t)(acc[j] * 0.0625f);
        tpad[(size_t)gm * 32 + 16 + r] = (bf16_t)0.f;
    }
}

// ------------------------------------------------------------------
// Kernel 4: 256x256 GEMM, m201-style 4-phase/tile with DEEP staging lead.
//   LDS: [parity][slot: A0,A1,B0,B1][128x64] bf16 = 128 KiB.
//   Tile t phases: (0,0) (0,1) (1,1) (1,0); issues at t: ph1->A0,B0(t+2),
//   ph2->B1(t+2), ph3->A1(t+2)  => every chunk has >=6-phase lead.
//   Guards (end of phase, before 2nd barrier): vmcnt(10)/(12)/-/(12) steady.
// ------------------------------------------------------------------
#define LGKM0  asm volatile("s_waitcnt lgkmcnt(0)" ::: "memory")
#define SBAR   __builtin_amdgcn_s_barrier()
#define SCHEDB __builtin_amdgcn_sched_barrier(0)
#define PRIO1  __builtin_amdgcn_s_setprio(1)
#define PRIO0  __builtin_amdgcn_s_setprio(0)
#define VMG(TXT) asm volatile("s_waitcnt " TXT ::: "memory")

#define MFMA_Q(AREG, BREG, QM, QN)                                             \
    _Pragma("unroll") for (int s_ = 0; s_ < 2; ++s_)                           \
    _Pragma("unroll") for (int i_ = 0; i_ < 4; ++i_)                           \
    _Pragma("unroll") for (int jj_ = 0; jj_ < 2; ++jj_)                        \
        acc[(QM)*4 + i_][(QN)*2 + jj_] =                                       \
            __builtin_amdgcn_mfma_f32_16x16x32_bf16(                           \
                AREG[i_][s_], BREG[jj_][s_], acc[(QM)*4 + i_][(QN)*2 + jj_],   \
                0, 0, 0);

// Phases of one K-tile. ISSx are statements; Gx are "vmcnt(N)" strings.
#define TILE_BODY(CP, ISS1, ISS2, ISS3, G0TXT, G1TXT, G3TXT)                   \
  {                                                                            \
    const bf16_t* A0s = &lds[CP][0][0];                                        \
    const bf16_t* A1s = &lds[CP][1][0];                                        \
    const bf16_t* B0s = &lds[CP][2][0];                                        \
    const bf16_t* B1s = &lds[CP][3][0];                                        \
    bf16x8 aA[4][2], aB[4][2], bA[2][2], bB[2][2];                             \
    /* ---- phase 0: (0,0) ---- */                                             \
    loadA(A0s, aA); loadB(B0s, bA);                                            \
    SCHEDB; SBAR; LGKM0; SCHEDB;                                               \
    PRIO1; MFMA_Q(aA, bA, 0, 0); PRIO0;                                        \
    VMG(G0TXT); SCHEDB; SBAR; SCHEDB;                                          \
    /* ---- phase 1: (0,1) ---- */                                             \
    loadB(B1s, bB);                                                            \
    ISS1;                                                                      \
    SCHEDB; SBAR; LGKM0; SCHEDB;                                               \
    PRIO1; MFMA_Q(aA, bB, 0, 1); PRIO0;                                        \
    VMG(G1TXT); SCHEDB; SBAR; SCHEDB;                                          \
    /* ---- phase 2: (1,1) ---- */                                             \
    loadA(A1s, aB);                                                            \
    ISS2;                                                                      \
    SCHEDB; SBAR; LGKM0; SCHEDB;                                               \
    PRIO1; MFMA_Q(aB, bB, 1, 1); PRIO0;                                        \
    SCHEDB; SBAR; SCHEDB;                                                      \
    /* ---- phase 3: (1,0) ---- */                                             \
    ISS3;                                                                      \
    SCHEDB; SBAR; SCHEDB;                                                      \
    PRIO1; MFMA_Q(aB, bA, 1, 0); PRIO0;                                        \
    VMG(G3TXT); SCHEDB; SBAR; SCHEDB;                                          \
  }

__global__ __launch_bounds__(512, 2) void gemm8_kernel(
    const bf16_t* __restrict__ xb, const bf16_t* __restrict__ Wb,
    const float* __restrict__ bias,
    const bf16_t* __restrict__ tpad, const bf16_t* __restrict__ Btp,
    float* __restrict__ out) {
    __shared__ __align__(16) bf16_t lds[2][4][128 * 64];   // 128 KiB

    int tid = threadIdx.x;
    int w = tid >> 6, l = tid & 63;
    int wm = w >> 2, wn = w & 3;        // 2M x 4N waves
    int l4 = l >> 4, l15 = l & 15;

    // XCD-bijective swizzle: nwg = 1024, 8 XCDs, 128 per XCD
    int orig = blockIdx.x;
    int id = (orig & 7) * 128 + (orig >> 3);
    int mb = id >> 4, nb = id & 15;
    int row0 = mb * 256, col0 = nb * 256;
    int b = row0 >> 11;

    f32x4 acc[8][4] = {};

    // stage one half-tile chunk (128 rows x 64 k): 2 loads/thread.
    // Dest linear, source pre-swizzled (rule 21).
    auto stageA = [&](int kt, int par, int half) {
        int k0 = kt * 64;
        const bf16_t* src = xb + (size_t)(row0 + half * 128) * DIN;
        bf16_t* dst = &lds[par][half][0];
#pragma unroll
        for (int ld = 0; ld < 2; ++ld) {
            int flat = ld * 512 + tid;
            int r = flat >> 3;
            int sc = (flat & 7) ^ (r & 7);
            __builtin_amdgcn_global_load_lds(
                GLP(src + (size_t)r * DIN + k0 + sc * 8),
                LDSP(dst + flat * 8), 16, 0, 0);
        }
    };
    auto stageB = [&](int kt, int par, int half) {
        int k0 = kt * 64;
        const bf16_t* src = Wb + (size_t)(col0 + half * 128) * DIN;
        bf16_t* dst = &lds[par][2 + half][0];
#pragma unroll
        for (int ld = 0; ld < 2; ++ld) {
            int flat = ld * 512 + tid;
            int r = flat >> 3;
            int sc = (flat & 7) ^ (r & 7);
            __builtin_amdgcn_global_load_lds(
                GLP(src + (size_t)r * DIN + k0 + sc * 8),
                LDSP(dst + flat * 8), 16, 0, 0);
        }
    };
    // adapter (256 x 32 each, linear) into buf0 slots A0 (adp-A), B0 (adp-B)
    auto stageAdpA = [&]() {
#pragma unroll
        for (int ld = 0; ld < 2; ++ld) {
            int flat = ld * 512 + tid;
            int r = flat >> 2, c4 = flat & 3;
            __builtin_amdgcn_global_load_lds(
                GLP(tpad + (size_t)(row0 + r) * 32 + c4 * 8),
                LDSP(&lds[0][0][flat * 8]), 16, 0, 0);
        }
    };
    auto stageAdpB = [&]() {
#pragma unroll
        for (int ld = 0; ld < 2; ++ld) {
            int flat = ld * 512 + tid;
            int r = flat >> 2, c4 = flat & 3;
            __builtin_amdgcn_global_load_lds(
                GLP(Btp + ((size_t)b * DOUT + col0 + r) * 32 + c4 * 8),
                LDSP(&lds[0][2][flat * 8]), 16, 0, 0);
        }
    };

    auto loadA = [&](const bf16_t* base, bf16x8 (&ar)[4][2]) {
#pragma unroll
        for (int i = 0; i < 4; ++i) {
            int row = wm * 64 + i * 16 + l15;
#pragma unroll
            for (int s = 0; s < 2; ++s)
                ar[i][s] = *(const bf16x8*)(base + row * 64 +
                                            (((s * 4 + l4) ^ (l15 & 7)) << 3));
        }
    };
    auto loadB = [&](const bf16_t* base, bf16x8 (&br)[2][2]) {
#pragma unroll
        for (int jj = 0; jj < 2; ++jj) {
            int row = wn * 32 + jj * 16 + l15;
#pragma unroll
            for (int s = 0; s < 2; ++s)
                br[jj][s] = *(const bf16x8*)(base + row * 64 +
                                             (((s * 4 + l4) ^ (l15 & 7)) << 3));
        }
    };

    // prologue: stage tiles 0 and 1 fully, in read order
    stageA(0, 0, 0); stageB(0, 0, 0); stageB(0, 0, 1); stageA(0, 0, 1);
    stageA(1, 1, 0); stageB(1, 1, 0); stageB(1, 1, 1); stageA(1, 1, 1);
    VMG("vmcnt(12)");        // A0(0),B0(0) landed; 6 chunks in flight
    SCHEDB; SBAR; SCHEDB;

#pragma unroll 1
    for (int j = 0; j < 62; ++j) {
        int cp = j & 1;
        TILE_BODY(cp,
                  { stageA(j + 2, cp, 0); stageB(j + 2, cp, 0); },
                  { stageB(j + 2, cp, 1); },
                  { stageA(j + 2, cp, 1); },
                  "vmcnt(10)", "vmcnt(12)", "vmcnt(12)");
    }
    // tile 62 (parity 0): adapter staged at ph1 into freed buf0 A0/B0 slots
    TILE_BODY(0,
              { stageAdpA(); stageAdpB(); },
              {}, {},
              "vmcnt(10)", "vmcnt(12)", "vmcnt(8)");
    // tile 63 (parity 1): no issues; tail guards
    TILE_BODY(1,
              {}, {}, {},
              "vmcnt(6)", "vmcnt(4)", "vmcnt(0)");

    // adapter K=32 MFMA step from buf0 slots A0 (adp-A) / B0 (adp-B)
    {
        const bf16_t* A0 = &lds[0][0][0];
        const bf16_t* B0 = &lds[0][2][0];
        bf16x8 aa[8]; bf16x8 bb[4];
#pragma unroll
        for (int ai = 0; ai < 8; ++ai) {
            int row = (ai >> 2) * 128 + wm * 64 + (ai & 3) * 16 + l15;
            aa[ai] = *(const bf16x8*)(A0 + row * 32 + l4 * 8);
        }
#pragma unroll
        for (int bj = 0; bj < 4; ++bj) {
            int row = (bj >> 1) * 128 + wn * 32 + (bj & 1) * 16 + l15;
            bb[bj] = *(const bf16x8*)(B0 + row * 32 + l4 * 8);
        }
#pragma unroll
        for (int ai = 0; ai < 8; ++ai)
#pragma unroll
            for (int bj = 0; bj < 4; ++bj)
                acc[ai][bj] = __builtin_amdgcn_mfma_f32_16x16x32_bf16(
                    aa[ai], bb[bj], acc[ai][bj], 0, 0, 0);
    }

    // ---- epilogue: + bias, store f32 ----
#pragma unroll
    for (int ai = 0; ai < 8; ++ai) {
        int gm = row0 + (ai >> 2) * 128 + wm * 64 + (ai & 3) * 16 + l4 * 4;
#pragma unroll
        for (int bj = 0; bj < 4; ++bj) {
            int gn = col0 + (bj >> 1) * 128 + wn * 32 + (bj & 1) * 16 + l15;
            float bsv = bias[gn];
#pragma unroll
            for (int q = 0; q < 4; ++q)
                out[(size_t)(gm + q) * DOUT + gn] = acc[ai][bj][q] + bsv;
        }
    }
}

// ------------------------------------------------------------------
// Fallback GEMM (m97 structure) for small-workspace paths
// ------------------------------------------------------------------
template<bool WPRE>
__global__ __launch_bounds__(256) void gemm_kernel(
    const float* __restrict__ xf,
    const float* __restrict__ Wf, const bf16_t* __restrict__ Wb,
    const float* __restrict__ bias,
    const bf16_t* __restrict__ tpad, const bf16_t* __restrict__ Btp,
    float* __restrict__ out) {
    __shared__ __align__(16) bf16_t As[128 * 64];
    __shared__ __align__(16) bf16_t Bs[128 * 64];

    int orig = blockIdx.x;
    int id = (orig & 7) * 512 + (orig >> 3);
    int mb = id >> 5, nb = id & 31;
    int row0 = mb * 128, col0 = nb * 128;
    int b = row0 >> 11;

    int tid = threadIdx.x;
    int w = tid >> 6, l = tid & 63;
    int wm = w >> 1, wn = w & 1;

    f32x4 acc[4][4] = {};

    for (int k0 = 0; k0 < DIN; k0 += 64) {
#pragma unroll
        for (int i = 0; i < 4; ++i) {
            int flat = i * 256 + tid;
            int row = flat >> 3, c8 = flat & 7;
            const float* src = xf + (size_t)(row0 + row) * DIN + k0 + c8 * 8;
            float4 v0 = *(const float4*)src;
            float4 v1 = *(const float4*)(src + 4);
            *(bf16x8*)(&As[flat * 8]) = cvt8(v0, v1);
        }
        if constexpr (WPRE) {
#pragma unroll
            for (int i = 0; i < 4; ++i) {
                int flat = i * 256 + tid;
                int row = flat >> 3, c8 = flat & 7;
                __builtin_amdgcn_global_load_lds(
                    GLP(Wb + (size_t)(col0 + row) * DIN + k0 + c8 * 8),
                    LDSP(&Bs[flat * 8]), 16, 0, 0);
            }
        } else {
#pragma unroll
            for (int i = 0; i < 4; ++i) {
                int flat = i * 256 + tid;
                int row = flat >> 3, c8 = flat & 7;
                const float* src = Wf + (size_t)(col0 + row) * DIN + k0 + c8 * 8;
                float4 v0 = *(const float4*)src;
                float4 v1 = *(const float4*)(src + 4);
                *(bf16x8*)(&Bs[flat * 8]) = cvt8(v0, v1);
            }
        }
        __syncthreads();
#pragma unroll
        for (int s = 0; s < 2; ++s) {
            int kr = s * 32 + (l >> 4) * 8;
            bf16x8 a[4], bf[4];
#pragma unroll
            for (int i = 0; i < 4; ++i)
                a[i] = *(const bf16x8*)(&As[(wm * 64 + i * 16 + (l & 15)) * 64 + kr]);
#pragma unroll
            for (int j = 0; j < 4; ++j)
                bf[j] = *(const bf16x8*)(&Bs[(wn * 64 + j * 16 + (l & 15)) * 64 + kr]);
#pragma unroll
            for (int i = 0; i < 4; ++i)
#pragma unroll
                for (int j = 0; j < 4; ++j)
                    acc[i][j] = __builtin_amdgcn_mfma_f32_16x16x32_bf16(a[i], bf[j], acc[i][j], 0, 0, 0);
        }
        __syncthreads();
    }

    {
#pragma unroll
        for (int i = 0; i < 2; ++i) {
            int flat = i * 256 + tid;
            int row = flat >> 2, c8 = flat & 3;
            __builtin_amdgcn_global_load_lds(
                GLP(tpad + (size_t)(row0 + row) * 32 + c8 * 8),
                LDSP(&As[flat * 8]), 16, 0, 0);
            __builtin_amdgcn_global_load_lds(
                GLP(Btp + ((size_t)b * DOUT + col0 + row) * 32 + c8 * 8),
                LDSP(&Bs[flat * 8]), 16, 0, 0);
        }
        __syncthreads();
        int kr = (l >> 4) * 8;
        bf16x8 a[4], bf[4];
#pragma unroll
        for (int i = 0; i < 4; ++i)
            a[i] = *(const bf16x8*)(&As[(wm * 64 + i * 16 + (l & 15)) * 32 + kr]);
#pragma unroll
        for (int j = 0; j < 4; ++j)
            bf[j] = *(const bf16x8*)(&Bs[(wn * 64 + j * 16 + (l & 15)) * 32 + kr]);
#pragma unroll
        for (int i = 0; i < 4; ++i)
#pragma unroll
            for (int j = 0; j < 4; ++j)
                acc[i][j] = __builtin_amdgcn_mfma_f32_16x16x32_bf16(a[i], bf[j], acc[i][j], 0, 0, 0);
    }

#pragma unroll
    for (int i = 0; i < 4; ++i) {
        int gm = row0 + wm * 64 + i * 16 + (l >> 4) * 4;
#pragma unroll
        for (int j = 0; j < 4; ++j) {
            int gn = col0 + wn * 64 + j * 16 + (l & 15);
            float bs = bias[gn];
#pragma unroll
            for (int q = 0; q < 4; ++q)
                out[(size_t)(gm + q) * DOUT + gn] = acc[i][j][q] + bs;
        }
    }
}

// ------------------------------------------------------------------
extern "C" void kernel_launch(void* const* d_in, const int* in_sizes, int n_in,
                              void* d_out, int out_size, void* d_ws, size_t ws_size,
                              hipStream_t stream) {
    const float* x        = (const float*)d_in[0];
    const int*   task_ids = (const int*)d_in[1];
    const float* W        = (const float*)d_in[2];
    const float* bias     = (const float*)d_in[3];
    const float* logits   = (const float*)d_in[4];
    const float* lora_a   = (const float*)d_in[5];
    const float* lora_b   = (const float*)d_in[6];
    float* out = (float*)d_out;

    char* ws = (char*)d_ws;
    size_t off = 0;
    auto alloc = [&](size_t bytes) {
        char* p = ws + off;
        off += (bytes + 255) & ~(size_t)255;
        return p;
    };
    bf16_t* Abt  = (bf16_t*)alloc((size_t)BS * RANK * DIN * 2);
    bf16_t* Btp  = (bf16_t*)alloc((size_t)BS * DOUT * 32 * 2);
    bf16_t* tpad = (bf16_t*)alloc((size_t)MTOT * 32 * 2);
    bf16_t* Wb   = (bf16_t*)alloc((size_t)DOUT * DIN * 2);
    size_t w_end = off;
    bf16_t* xb   = (bf16_t*)alloc((size_t)MTOT * DIN * 2);
    size_t full_end = off;

    bool wpre = ws_size >= w_end;
    bool xpre = ws_size >= full_end;

    mix_kernel<<<dim3(64, 8), 256, 0, stream>>>(logits, task_ids, lora_a, lora_b, Abt, Btp);
    if (wpre)
        convw_kernel<<<(DOUT * DIN / 8) / 256, 256, 0, stream>>>(W, Wb);
    if (xpre)
        tconv_kernel<true><<<MTOT / 64, 256, 0, stream>>>(x, Abt, xb, tpad);
    else
        tconv_kernel<false><<<MTOT / 64, 256, 0, stream>>>(x, Abt, nullptr, tpad);

    if (xpre) {
        int nblk = (MTOT / 256) * (DOUT / 256);   // 1024
        gemm8_kernel<<<nblk, 512, 0, stream>>>(xb, Wb, bias, tpad, Btp, out);
    } else {
        int nblk = (MTOT / 128) * (DOUT / 128);   // 4096
        if (wpre)
            gemm_kernel<true><<<nblk, 256, 0, stream>>>(x, W, Wb, bias, tpad, Btp, out);
        else
            gemm_kernel<false><<<nblk, 256, 0, stream>>>(x, W, Wb, bias, tpad, Btp, out);
    }
}